// Round 1
// baseline (257.694 us; speedup 1.0000x reference)
//
#include <hip/hip_runtime.h>
#include <hip/hip_bf16.h>
#include <stdint.h>

// Problem: B=4096, I=H=1024. pre_ih = x@w_ih^T, pre_hh = h@w_hh^T (each 4096x4096,
// K=1024), per-gate LN over H, gate math, c_new LN, outputs h_new||c_new (fp32).

#define HDIM 1024
#define BATCH 4096
#define NGATE 4096   /* 4*H */
#define KDIM 1024

typedef __bf16 bf16x8 __attribute__((ext_vector_type(8)));
typedef float f32x4 __attribute__((ext_vector_type(4)));

__device__ __forceinline__ unsigned short f2bf(float f) {
  unsigned int u = __builtin_bit_cast(unsigned int, f);
  unsigned int r = (u + 0x7fffu + ((u >> 16) & 1u)) >> 16;
  return (unsigned short)r;
}

__device__ __forceinline__ float bf2f(unsigned short s) {
  unsigned int u = ((unsigned int)s) << 16;
  return __builtin_bit_cast(float, u);
}

__device__ __forceinline__ void gl_lds16(const void* g, void* l) {
  // async global->LDS, 16B per lane; LDS dest = wave-uniform base + lane*16
  __builtin_amdgcn_global_load_lds(
      (__attribute__((address_space(1))) unsigned int*)g,
      (__attribute__((address_space(3))) unsigned int*)l,
      16, 0, 0);
}

// ---------------- cast fp32 -> bf16 (x, h, w_ih, w_hh) ----------------
__global__ __launch_bounds__(256) void cast_bf16_kernel(
    const float* __restrict__ x, const float* __restrict__ h,
    const float* __restrict__ wi, const float* __restrict__ wh,
    unsigned short* __restrict__ xb, unsigned short* __restrict__ hb,
    unsigned short* __restrict__ wib, unsigned short* __restrict__ whb) {
  const float* src;
  unsigned short* dst;
  switch (blockIdx.y) {
    case 0: src = x;  dst = xb;  break;
    case 1: src = h;  dst = hb;  break;
    case 2: src = wi; dst = wib; break;
    default: src = wh; dst = whb; break;
  }
  size_t i = ((size_t)blockIdx.x * 256 + threadIdx.x) * 4;
  float4 v = *(const float4*)(src + i);
  ushort4 o;
  o.x = f2bf(v.x); o.y = f2bf(v.y); o.z = f2bf(v.z); o.w = f2bf(v.w);
  *(ushort4*)(dst + i) = o;
}

// ---------------- bf16 MFMA GEMM: C[m][n] = sum_k A[m][k]*B[n][k] ----------------
// BM=BN=128, BK=32. block=256 (4 waves, 2x2), each wave 64x64 = 4x4 MFMA tiles.
__global__ __launch_bounds__(256, 2) void gemm_bt_kernel(
    const unsigned short* __restrict__ A0, const unsigned short* __restrict__ B0,
    unsigned short* __restrict__ C0,
    const unsigned short* __restrict__ A1, const unsigned short* __restrict__ B1,
    unsigned short* __restrict__ C1) {
  const unsigned short* A = blockIdx.z ? A1 : A0;
  const unsigned short* B = blockIdx.z ? B1 : B0;
  unsigned short* C = blockIdx.z ? C1 : C0;

  __shared__ alignas(16) unsigned short As[128 * 32];
  __shared__ alignas(16) unsigned short Bs[128 * 32];

  const int tid = threadIdx.x;
  const int wave = tid >> 6;
  const int lane = tid & 63;
  const int bm = blockIdx.x * 128;
  const int bn = blockIdx.y * 128;
  const int wm = (wave >> 1) * 64;
  const int wn = (wave & 1) * 64;

  const int srow = lane >> 2;        // 0..15 within a 16-row staging chunk
  const int scol = (lane & 3) * 8;   // k-element offset (8 bf16 = 16B)

  f32x4 acc[4][4];
#pragma unroll
  for (int i = 0; i < 4; ++i)
#pragma unroll
    for (int j = 0; j < 4; ++j)
#pragma unroll
      for (int r = 0; r < 4; ++r) acc[i][j][r] = 0.0f;

  const int m15 = lane & 15;
  const int quad = lane >> 4;

  for (int k0 = 0; k0 < KDIM; k0 += 32) {
    // stage A(128x32) and B(128x32): each wave covers 32 rows of each (2 insts)
#pragma unroll
    for (int t = 0; t < 2; ++t) {
      int chunk = wave * 32 + t * 16;      // wave-uniform row base
      int row = chunk + srow;
      gl_lds16(A + (size_t)(bm + row) * KDIM + k0 + scol, &As[chunk * 32]);
      gl_lds16(B + (size_t)(bn + row) * KDIM + k0 + scol, &Bs[chunk * 32]);
    }
    __syncthreads();  // compiler emits s_waitcnt vmcnt(0) before s_barrier

    bf16x8 af[4], bfr[4];
#pragma unroll
    for (int i = 0; i < 4; ++i)
      af[i] = *(const bf16x8*)&As[(wm + i * 16 + m15) * 32 + quad * 8];
#pragma unroll
    for (int j = 0; j < 4; ++j)
      bfr[j] = *(const bf16x8*)&Bs[(wn + j * 16 + m15) * 32 + quad * 8];

#pragma unroll
    for (int i = 0; i < 4; ++i)
#pragma unroll
      for (int j = 0; j < 4; ++j)
        acc[i][j] = __builtin_amdgcn_mfma_f32_16x16x32_bf16(af[i], bfr[j], acc[i][j], 0, 0, 0);

    __syncthreads();
  }

  // D layout: row m = (lane>>4)*4 + r, col n = lane&15  [m89/m91 verified]
#pragma unroll
  for (int i = 0; i < 4; ++i)
#pragma unroll
    for (int j = 0; j < 4; ++j)
#pragma unroll
      for (int r = 0; r < 4; ++r) {
        int m = bm + wm + i * 16 + quad * 4 + r;
        int n = bn + wn + j * 16 + m15;
        C[(size_t)m * NGATE + n] = f2bf(acc[i][j][r]);
      }
}

// ---------------- LN + gates + cell update ----------------
__device__ __forceinline__ void block_sum4(float v[4], float* lds, int tid) {
#pragma unroll
  for (int o = 32; o > 0; o >>= 1)
#pragma unroll
    for (int k = 0; k < 4; ++k) v[k] += __shfl_down(v[k], o, 64);
  __syncthreads();
  if ((tid & 63) == 0) {
    int w = tid >> 6;
#pragma unroll
    for (int k = 0; k < 4; ++k) lds[w * 4 + k] = v[k];
  }
  __syncthreads();
#pragma unroll
  for (int k = 0; k < 4; ++k) v[k] = lds[k] + lds[4 + k] + lds[8 + k] + lds[12 + k];
}

__device__ __forceinline__ float sigmoidf_(float x) {
  return 1.0f / (1.0f + __expf(-x));
}

__global__ __launch_bounds__(256) void ln_gate_kernel(
    const unsigned short* __restrict__ pih, const unsigned short* __restrict__ phh,
    const float* __restrict__ c, const float* __restrict__ b_ih,
    const float* __restrict__ gamma, const float* __restrict__ beta,
    float* __restrict__ h_out, float* __restrict__ c_out) {
  __shared__ float lds[16];
  const int b = blockIdx.x;
  const int t = threadIdx.x;
  const float inv_h = 1.0f / 1024.0f;
  const float eps = 1e-5f;

  float gate[4][4];  // [gate][r]

#pragma unroll
  for (int g = 0; g < 4; ++g) {
    float vih[4], vhh[4];
    float red[4] = {0.f, 0.f, 0.f, 0.f};  // {sum_ih, sq_ih, sum_hh, sq_hh}
#pragma unroll
    for (int r = 0; r < 4; ++r) {
      int j = t + 256 * r;
      float a = bf2f(pih[(size_t)b * NGATE + g * HDIM + j]);
      float e = bf2f(phh[(size_t)b * NGATE + g * HDIM + j]);
      vih[r] = a; vhh[r] = e;
      red[0] += a; red[1] += a * a; red[2] += e; red[3] += e * e;
    }
    block_sum4(red, lds, t);
    float mu0 = red[0] * inv_h;
    float rs0 = rsqrtf(red[1] * inv_h - mu0 * mu0 + eps);
    float mu1 = red[2] * inv_h;
    float rs1 = rsqrtf(red[3] * inv_h - mu1 * mu1 + eps);
#pragma unroll
    for (int r = 0; r < 4; ++r) {
      int j = t + 256 * r;
      float gih = gamma[(2 * g) * HDIM + j] * ((vih[r] - mu0) * rs0) + beta[(2 * g) * HDIM + j];
      float ghh = gamma[(2 * g + 1) * HDIM + j] * ((vhh[r] - mu1) * rs1) + beta[(2 * g + 1) * HDIM + j];
      gate[g][r] = gih + ghh + b_ih[g * HDIM + j];
    }
  }

  float cn[4], ov[4];
  float red2[4] = {0.f, 0.f, 0.f, 0.f};
#pragma unroll
  for (int r = 0; r < 4; ++r) {
    int j = t + 256 * r;
    float iv = sigmoidf_(gate[0][r]);
    float fv = sigmoidf_(gate[1][r]);
    float av = tanhf(gate[2][r]);
    ov[r] = sigmoidf_(gate[3][r]);
    float cv = fv * c[(size_t)b * HDIM + j] + iv * av;
    cn[r] = cv;
    red2[0] += cv; red2[1] += cv * cv;
  }
  block_sum4(red2, lds, t);
  float mu = red2[0] * inv_h;
  float rs = rsqrtf(red2[1] * inv_h - mu * mu + eps);
#pragma unroll
  for (int r = 0; r < 4; ++r) {
    int j = t + 256 * r;
    float ln = gamma[8 * HDIM + j] * ((cn[r] - mu) * rs) + beta[8 * HDIM + j];
    h_out[(size_t)b * HDIM + j] = ov[r] * tanhf(ln);
    c_out[(size_t)b * HDIM + j] = cn[r];
  }
}

extern "C" void kernel_launch(void* const* d_in, const int* in_sizes, int n_in,
                              void* d_out, int out_size, void* d_ws, size_t ws_size,
                              hipStream_t stream) {
  const float* x     = (const float*)d_in[0];
  const float* h     = (const float*)d_in[1];
  const float* c     = (const float*)d_in[2];
  const float* w_ih  = (const float*)d_in[3];
  const float* w_hh  = (const float*)d_in[4];
  const float* b_ih  = (const float*)d_in[5];
  const float* gamma = (const float*)d_in[6];
  const float* beta  = (const float*)d_in[7];
  // d_in[8] = time (unused)

  // workspace layout (bytes):
  //   0        xb   bf16 4096x1024  ( 8 MB)
  //   8M       hb   bf16 4096x1024  ( 8 MB)
  //   16M      wib  bf16 4096x1024  ( 8 MB)
  //   24M      whb  bf16 4096x1024  ( 8 MB)
  //   32M      pih  bf16 4096x4096  (32 MB)
  //   64M      phh  bf16 4096x4096  (32 MB)   total 96 MB
  char* ws = (char*)d_ws;
  unsigned short* xb  = (unsigned short*)(ws);
  unsigned short* hb  = (unsigned short*)(ws + (size_t)8 * 1024 * 1024);
  unsigned short* wib = (unsigned short*)(ws + (size_t)16 * 1024 * 1024);
  unsigned short* whb = (unsigned short*)(ws + (size_t)24 * 1024 * 1024);
  unsigned short* pih = (unsigned short*)(ws + (size_t)32 * 1024 * 1024);
  unsigned short* phh = (unsigned short*)(ws + (size_t)64 * 1024 * 1024);

  dim3 cgrid(4096, 4, 1);  // 4 arrays x 4M elems, 4 elems/thread
  cast_bf16_kernel<<<cgrid, 256, 0, stream>>>(x, h, w_ih, w_hh, xb, hb, wib, whb);

  dim3 ggrid(32, 32, 2);   // 128x128 tiles over 4096x4096; z: 0=ih, 1=hh
  gemm_bt_kernel<<<ggrid, 256, 0, stream>>>(xb, wib, pih, hb, whb, phh);

  float* h_out = (float*)d_out;
  float* c_out = h_out + (size_t)BATCH * HDIM;
  ln_gate_kernel<<<4096, 256, 0, stream>>>(pih, phh, c, b_ih, gamma, beta, h_out, c_out);
}

// Round 2
// 250.780 us; speedup vs baseline: 1.0276x; 1.0276x over previous
//
#include <hip/hip_runtime.h>
#include <hip/hip_bf16.h>
#include <stdint.h>

// Problem: B=4096, I=H=1024. pre_ih = x@w_ih^T, pre_hh = h@w_hh^T (each 4096x4096,
// K=1024), per-gate LN over H, gate math, c_new LN, outputs h_new||c_new (fp32).

#define HDIM 1024
#define BATCH 4096
#define NGATE 4096   /* 4*H */
#define KDIM 1024

typedef __bf16 bf16x8 __attribute__((ext_vector_type(8)));
typedef float f32x4 __attribute__((ext_vector_type(4)));

__device__ __forceinline__ unsigned short f2bf(float f) {
  unsigned int u = __builtin_bit_cast(unsigned int, f);
  unsigned int r = (u + 0x7fffu + ((u >> 16) & 1u)) >> 16;
  return (unsigned short)r;
}

__device__ __forceinline__ float bf2f(unsigned short s) {
  unsigned int u = ((unsigned int)s) << 16;
  return __builtin_bit_cast(float, u);
}

__device__ __forceinline__ void gl_lds16(const void* g, void* l) {
  // async global->LDS, 16B per lane; LDS dest = wave-uniform base + lane*16
  __builtin_amdgcn_global_load_lds(
      (__attribute__((address_space(1))) unsigned int*)g,
      (__attribute__((address_space(3))) unsigned int*)l,
      16, 0, 0);
}

// ---------------- cast fp32 -> bf16 (x, h, w_ih, w_hh) ----------------
__global__ __launch_bounds__(256) void cast_bf16_kernel(
    const float* __restrict__ x, const float* __restrict__ h,
    const float* __restrict__ wi, const float* __restrict__ wh,
    unsigned short* __restrict__ xb, unsigned short* __restrict__ hb,
    unsigned short* __restrict__ wib, unsigned short* __restrict__ whb) {
  const float* src;
  unsigned short* dst;
  switch (blockIdx.y) {
    case 0: src = x;  dst = xb;  break;
    case 1: src = h;  dst = hb;  break;
    case 2: src = wi; dst = wib; break;
    default: src = wh; dst = whb; break;
  }
  size_t i = ((size_t)blockIdx.x * 256 + threadIdx.x) * 4;
  float4 v = *(const float4*)(src + i);
  ushort4 o;
  o.x = f2bf(v.x); o.y = f2bf(v.y); o.z = f2bf(v.z); o.w = f2bf(v.w);
  *(ushort4*)(dst + i) = o;
}

// ---------------- bf16 MFMA GEMM: C[m][n] = sum_k A[m][k]*B[n][k] ----------------
// BM=BN=128, BK=32. block=256 (4 waves, 2x2), each wave 64x64 = 4x4 MFMA tiles.
// LDS layout is XOR-swizzled: row r's k-chunk c8 (16B granules, c8 in 0..3) is
// stored at position p = c8 ^ s(r), s(r) = (r>>1)&3. Applied at fetch (since
// global_load_lds pins LDS dest to lane*16) and inverted at ds_read. This puts
// the 16 lanes of each ds_read_b128 quarter-phase on all 8 four-bank groups
// (2 lanes each = conflict-free) instead of 2 groups (8 lanes = 4-way).
__global__ __launch_bounds__(256, 2) void gemm_bt_kernel(
    const unsigned short* __restrict__ A0, const unsigned short* __restrict__ B0,
    unsigned short* __restrict__ C0,
    const unsigned short* __restrict__ A1, const unsigned short* __restrict__ B1,
    unsigned short* __restrict__ C1) {
  const unsigned short* A = blockIdx.z ? A1 : A0;
  const unsigned short* B = blockIdx.z ? B1 : B0;
  unsigned short* C = blockIdx.z ? C1 : C0;

  __shared__ alignas(16) unsigned short As[128 * 32];
  __shared__ alignas(16) unsigned short Bs[128 * 32];

  const int tid = threadIdx.x;
  const int wave = tid >> 6;
  const int lane = tid & 63;
  const int bm = blockIdx.x * 128;
  const int bn = blockIdx.y * 128;
  const int wm = (wave >> 1) * 64;
  const int wn = (wave & 1) * 64;

  const int srow = lane >> 2;  // 0..15 within a 16-row staging chunk
  // fetch-side swizzle: this lane's 16B granule holds k-chunk (lane&3)^s(row),
  // s(row) = (row>>1)&3 = ((lane>>2)>>1)&3 (chunk bases are multiples of 16)
  const int scol = (((lane & 3) ^ ((lane >> 3) & 3)) * 8);

  f32x4 acc[4][4];
#pragma unroll
  for (int i = 0; i < 4; ++i)
#pragma unroll
    for (int j = 0; j < 4; ++j)
#pragma unroll
      for (int r = 0; r < 4; ++r) acc[i][j][r] = 0.0f;

  const int m15 = lane & 15;
  const int quad = lane >> 4;
  // read-side swizzle: row = (16-mult) + m15, so s(row) = (m15>>1)&3
  const int rdoff = ((quad ^ ((m15 >> 1) & 3)) * 8);

  for (int k0 = 0; k0 < KDIM; k0 += 32) {
    // stage A(128x32) and B(128x32): each wave covers 32 rows of each (2 insts)
#pragma unroll
    for (int t = 0; t < 2; ++t) {
      int chunk = wave * 32 + t * 16;  // wave-uniform row base
      int row = chunk + srow;
      gl_lds16(A + (size_t)(bm + row) * KDIM + k0 + scol, &As[chunk * 32]);
      gl_lds16(B + (size_t)(bn + row) * KDIM + k0 + scol, &Bs[chunk * 32]);
    }
    __syncthreads();  // compiler emits s_waitcnt vmcnt(0) before s_barrier

    bf16x8 af[4], bfr[4];
#pragma unroll
    for (int i = 0; i < 4; ++i)
      af[i] = *(const bf16x8*)&As[(wm + i * 16 + m15) * 32 + rdoff];
#pragma unroll
    for (int j = 0; j < 4; ++j)
      bfr[j] = *(const bf16x8*)&Bs[(wn + j * 16 + m15) * 32 + rdoff];

#pragma unroll
    for (int i = 0; i < 4; ++i)
#pragma unroll
      for (int j = 0; j < 4; ++j)
        acc[i][j] = __builtin_amdgcn_mfma_f32_16x16x32_bf16(af[i], bfr[j], acc[i][j], 0, 0, 0);

    __syncthreads();
  }

  // D layout: row m = (lane>>4)*4 + r, col n = lane&15  [m89/m91 verified]
#pragma unroll
  for (int i = 0; i < 4; ++i)
#pragma unroll
    for (int j = 0; j < 4; ++j)
#pragma unroll
      for (int r = 0; r < 4; ++r) {
        int m = bm + wm + i * 16 + quad * 4 + r;
        int n = bn + wn + j * 16 + m15;
        C[(size_t)m * NGATE + n] = f2bf(acc[i][j][r]);
      }
}

// ---------------- LN + gates + cell update ----------------
__device__ __forceinline__ void block_sum4(float v[4], float* lds, int tid) {
#pragma unroll
  for (int o = 32; o > 0; o >>= 1)
#pragma unroll
    for (int k = 0; k < 4; ++k) v[k] += __shfl_down(v[k], o, 64);
  __syncthreads();
  if ((tid & 63) == 0) {
    int w = tid >> 6;
#pragma unroll
    for (int k = 0; k < 4; ++k) lds[w * 4 + k] = v[k];
  }
  __syncthreads();
#pragma unroll
  for (int k = 0; k < 4; ++k) v[k] = lds[k] + lds[4 + k] + lds[8 + k] + lds[12 + k];
}

__device__ __forceinline__ float fast_sigmoid(float x) {
  return __builtin_amdgcn_rcpf(1.0f + __expf(-x));
}
__device__ __forceinline__ float fast_tanh(float x) {
  // 1 - 2/(exp(2x)+1); exp->inf gives 1, exp->0 gives -1 (correct saturation)
  return 1.0f - 2.0f * __builtin_amdgcn_rcpf(__expf(2.0f * x) + 1.0f);
}

__global__ __launch_bounds__(256) void ln_gate_kernel(
    const unsigned short* __restrict__ pih, const unsigned short* __restrict__ phh,
    const float* __restrict__ c, const float* __restrict__ b_ih,
    const float* __restrict__ gamma, const float* __restrict__ beta,
    float* __restrict__ h_out, float* __restrict__ c_out) {
  __shared__ float lds[16];
  const int b = blockIdx.x;
  const int t = threadIdx.x;
  const int j = t * 4;  // 4 contiguous elements per thread
  const float inv_h = 1.0f / 1024.0f;
  const float eps = 1e-5f;

  float gate[4][4];  // [gate][r]

#pragma unroll
  for (int g = 0; g < 4; ++g) {
    ushort4 a4 = *(const ushort4*)&pih[(size_t)b * NGATE + g * HDIM + j];
    ushort4 e4 = *(const ushort4*)&phh[(size_t)b * NGATE + g * HDIM + j];
    float vih[4] = {bf2f(a4.x), bf2f(a4.y), bf2f(a4.z), bf2f(a4.w)};
    float vhh[4] = {bf2f(e4.x), bf2f(e4.y), bf2f(e4.z), bf2f(e4.w)};
    float red[4] = {0.f, 0.f, 0.f, 0.f};  // {sum_ih, sq_ih, sum_hh, sq_hh}
#pragma unroll
    for (int r = 0; r < 4; ++r) {
      red[0] += vih[r]; red[1] += vih[r] * vih[r];
      red[2] += vhh[r]; red[3] += vhh[r] * vhh[r];
    }
    block_sum4(red, lds, t);
    float mu0 = red[0] * inv_h;
    float rs0 = rsqrtf(red[1] * inv_h - mu0 * mu0 + eps);
    float mu1 = red[2] * inv_h;
    float rs1 = rsqrtf(red[3] * inv_h - mu1 * mu1 + eps);
    float4 g0 = *(const float4*)&gamma[(2 * g) * HDIM + j];
    float4 b0 = *(const float4*)&beta[(2 * g) * HDIM + j];
    float4 g1 = *(const float4*)&gamma[(2 * g + 1) * HDIM + j];
    float4 b1 = *(const float4*)&beta[(2 * g + 1) * HDIM + j];
    float4 bb = *(const float4*)&b_ih[g * HDIM + j];
    const float* g0p = &g0.x; const float* b0p = &b0.x;
    const float* g1p = &g1.x; const float* b1p = &b1.x;
    const float* bbp = &bb.x;
#pragma unroll
    for (int r = 0; r < 4; ++r) {
      float gih = g0p[r] * ((vih[r] - mu0) * rs0) + b0p[r];
      float ghh = g1p[r] * ((vhh[r] - mu1) * rs1) + b1p[r];
      gate[g][r] = gih + ghh + bbp[r];
    }
  }

  float4 cv4 = *(const float4*)&c[(size_t)b * HDIM + j];
  const float* cvp = &cv4.x;
  float cn[4], ov[4];
  float red2[4] = {0.f, 0.f, 0.f, 0.f};
#pragma unroll
  for (int r = 0; r < 4; ++r) {
    float iv = fast_sigmoid(gate[0][r]);
    float fv = fast_sigmoid(gate[1][r]);
    float av = fast_tanh(gate[2][r]);
    ov[r] = fast_sigmoid(gate[3][r]);
    float cvn = fv * cvp[r] + iv * av;
    cn[r] = cvn;
    red2[0] += cvn; red2[1] += cvn * cvn;
  }
  block_sum4(red2, lds, t);
  float mu = red2[0] * inv_h;
  float rs = rsqrtf(red2[1] * inv_h - mu * mu + eps);

  float4 g8 = *(const float4*)&gamma[8 * HDIM + j];
  float4 b8 = *(const float4*)&beta[8 * HDIM + j];
  const float* g8p = &g8.x; const float* b8p = &b8.x;
  float4 ho, co;
  float* hop = &ho.x; float* cop = &co.x;
#pragma unroll
  for (int r = 0; r < 4; ++r) {
    float ln = g8p[r] * ((cn[r] - mu) * rs) + b8p[r];
    hop[r] = ov[r] * fast_tanh(ln);
    cop[r] = cn[r];
  }
  *(float4*)&h_out[(size_t)b * HDIM + j] = ho;
  *(float4*)&c_out[(size_t)b * HDIM + j] = co;
}

extern "C" void kernel_launch(void* const* d_in, const int* in_sizes, int n_in,
                              void* d_out, int out_size, void* d_ws, size_t ws_size,
                              hipStream_t stream) {
  const float* x     = (const float*)d_in[0];
  const float* h     = (const float*)d_in[1];
  const float* c     = (const float*)d_in[2];
  const float* w_ih  = (const float*)d_in[3];
  const float* w_hh  = (const float*)d_in[4];
  const float* b_ih  = (const float*)d_in[5];
  const float* gamma = (const float*)d_in[6];
  const float* beta  = (const float*)d_in[7];
  // d_in[8] = time (unused)

  // workspace layout (bytes):
  //   0        xb   bf16 4096x1024  ( 8 MB)
  //   8M       hb   bf16 4096x1024  ( 8 MB)
  //   16M      wib  bf16 4096x1024  ( 8 MB)
  //   24M      whb  bf16 4096x1024  ( 8 MB)
  //   32M      pih  bf16 4096x4096  (32 MB)
  //   64M      phh  bf16 4096x4096  (32 MB)   total 96 MB
  char* ws = (char*)d_ws;
  unsigned short* xb  = (unsigned short*)(ws);
  unsigned short* hb  = (unsigned short*)(ws + (size_t)8 * 1024 * 1024);
  unsigned short* wib = (unsigned short*)(ws + (size_t)16 * 1024 * 1024);
  unsigned short* whb = (unsigned short*)(ws + (size_t)24 * 1024 * 1024);
  unsigned short* pih = (unsigned short*)(ws + (size_t)32 * 1024 * 1024);
  unsigned short* phh = (unsigned short*)(ws + (size_t)64 * 1024 * 1024);

  dim3 cgrid(4096, 4, 1);  // 4 arrays x 4M elems, 4 elems/thread
  cast_bf16_kernel<<<cgrid, 256, 0, stream>>>(x, h, w_ih, w_hh, xb, hb, wib, whb);

  dim3 ggrid(32, 32, 2);   // 128x128 tiles over 4096x4096; z: 0=ih, 1=hh
  gemm_bt_kernel<<<ggrid, 256, 0, stream>>>(xb, wib, pih, hb, whb, phh);

  float* h_out = (float*)d_out;
  float* c_out = h_out + (size_t)BATCH * HDIM;
  ln_gate_kernel<<<4096, 256, 0, stream>>>(pih, phh, c, b_ih, gamma, beta, h_out, c_out);
}

// Round 3
// 248.513 us; speedup vs baseline: 1.0369x; 1.0091x over previous
//
#include <hip/hip_runtime.h>
#include <hip/hip_bf16.h>
#include <stdint.h>

// Problem: B=4096, I=H=1024. pre_ih = x@w_ih^T, pre_hh = h@w_hh^T (each 4096x4096,
// K=1024), per-gate LN over H, gate math, c_new LN, outputs h_new||c_new (fp32).

#define HDIM 1024
#define BATCH 4096
#define NGATE 4096   /* 4*H */
#define KDIM 1024

typedef __bf16 bf16x8 __attribute__((ext_vector_type(8)));
typedef float f32x4 __attribute__((ext_vector_type(4)));
typedef unsigned short ushort8_t __attribute__((ext_vector_type(8)));

__device__ __forceinline__ unsigned short f2bf(float f) {
  unsigned int u = __builtin_bit_cast(unsigned int, f);
  unsigned int r = (u + 0x7fffu + ((u >> 16) & 1u)) >> 16;
  return (unsigned short)r;
}

__device__ __forceinline__ float bf2f(unsigned short s) {
  unsigned int u = ((unsigned int)s) << 16;
  return __builtin_bit_cast(float, u);
}

__device__ __forceinline__ void gl_lds16(const void* g, void* l) {
  // async global->LDS, 16B per lane; LDS dest = wave-uniform base + lane*16
  __builtin_amdgcn_global_load_lds(
      (__attribute__((address_space(1))) unsigned int*)g,
      (__attribute__((address_space(3))) unsigned int*)l,
      16, 0, 0);
}

// ---------------- cast fp32 -> bf16 (x, h, w_ih, w_hh) ----------------
__global__ __launch_bounds__(256) void cast_bf16_kernel(
    const float* __restrict__ x, const float* __restrict__ h,
    const float* __restrict__ wi, const float* __restrict__ wh,
    unsigned short* __restrict__ xb, unsigned short* __restrict__ hb,
    unsigned short* __restrict__ wib, unsigned short* __restrict__ whb) {
  const float* src;
  unsigned short* dst;
  switch (blockIdx.y) {
    case 0: src = x;  dst = xb;  break;
    case 1: src = h;  dst = hb;  break;
    case 2: src = wi; dst = wib; break;
    default: src = wh; dst = whb; break;
  }
  size_t i = ((size_t)blockIdx.x * 256 + threadIdx.x) * 4;
  float4 v = *(const float4*)(src + i);
  ushort4 o;
  o.x = f2bf(v.x); o.y = f2bf(v.y); o.z = f2bf(v.z); o.w = f2bf(v.w);
  *(ushort4*)(dst + i) = o;
}

// ---------------- bf16 MFMA GEMM: C[m][n] = sum_k A[m][k]*B[n][k] ----------------
// BM=BN=128, BK=32. block=256 (4 waves, 2x2), each wave 64x64 = 4x4 MFMA tiles.
// LDS XOR-swizzle (fetch-side, inverted at ds_read) keeps SQ_LDS_BANK_CONFLICT=0.
// launch_bounds (256,4): VGPR 60 + AGPR 64 = 124 <= 128 -> 4 blocks/CU resident.
__global__ __launch_bounds__(256, 4) void gemm_bt_kernel(
    const unsigned short* __restrict__ A0, const unsigned short* __restrict__ B0,
    unsigned short* __restrict__ C0,
    const unsigned short* __restrict__ A1, const unsigned short* __restrict__ B1,
    unsigned short* __restrict__ C1) {
  const unsigned short* A = blockIdx.z ? A1 : A0;
  const unsigned short* B = blockIdx.z ? B1 : B0;
  unsigned short* C = blockIdx.z ? C1 : C0;

  __shared__ alignas(16) unsigned short As[128 * 32];
  __shared__ alignas(16) unsigned short Bs[128 * 32];

  const int tid = threadIdx.x;
  const int wave = tid >> 6;
  const int lane = tid & 63;
  const int bm = blockIdx.x * 128;
  const int bn = blockIdx.y * 128;
  const int wm = (wave >> 1) * 64;
  const int wn = (wave & 1) * 64;

  const int srow = lane >> 2;  // 0..15 within a 16-row staging chunk
  // fetch-side swizzle: lane's 16B granule holds k-chunk (lane&3)^((lane>>3)&3)
  const int scol = (((lane & 3) ^ ((lane >> 3) & 3)) * 8);

  f32x4 acc[4][4];
#pragma unroll
  for (int i = 0; i < 4; ++i)
#pragma unroll
    for (int j = 0; j < 4; ++j)
#pragma unroll
      for (int r = 0; r < 4; ++r) acc[i][j][r] = 0.0f;

  const int m15 = lane & 15;
  const int quad = lane >> 4;
  // read-side swizzle inverse: row = 16k + m15 -> s(row) = (m15>>1)&3
  const int rdoff = ((quad ^ ((m15 >> 1) & 3)) * 8);

  for (int k0 = 0; k0 < KDIM; k0 += 32) {
#pragma unroll
    for (int t = 0; t < 2; ++t) {
      int chunk = wave * 32 + t * 16;  // wave-uniform row base
      int row = chunk + srow;
      gl_lds16(A + (size_t)(bm + row) * KDIM + k0 + scol, &As[chunk * 32]);
      gl_lds16(B + (size_t)(bn + row) * KDIM + k0 + scol, &Bs[chunk * 32]);
    }
    __syncthreads();

    bf16x8 af[4], bfr[4];
#pragma unroll
    for (int i = 0; i < 4; ++i)
      af[i] = *(const bf16x8*)&As[(wm + i * 16 + m15) * 32 + rdoff];
#pragma unroll
    for (int j = 0; j < 4; ++j)
      bfr[j] = *(const bf16x8*)&Bs[(wn + j * 16 + m15) * 32 + rdoff];

#pragma unroll
    for (int i = 0; i < 4; ++i)
#pragma unroll
      for (int j = 0; j < 4; ++j)
        acc[i][j] = __builtin_amdgcn_mfma_f32_16x16x32_bf16(af[i], bfr[j], acc[i][j], 0, 0, 0);

    __syncthreads();
  }

  // D layout: row m = (lane>>4)*4 + r, col n = lane&15  [m89/m91 verified]
#pragma unroll
  for (int i = 0; i < 4; ++i)
#pragma unroll
    for (int j = 0; j < 4; ++j)
#pragma unroll
      for (int r = 0; r < 4; ++r) {
        int m = bm + wm + i * 16 + quad * 4 + r;
        int n = bn + wn + j * 16 + m15;
        C[(size_t)m * NGATE + n] = f2bf(acc[i][j][r]);
      }
}

// ---------------- LN + gates + cell update ----------------
// One block per batch row b. Phase A: wave g computes LN stats for gate g
// (ih and hh) via wave-local butterfly reduction (no barriers), parks
// {mu0,rs0,mu1,rs1} in LDS. Phase B: all 256 threads re-load pre (L1/L2-hot,
// 16KB/block), normalize with broadcast stats, gate math, one block reduction
// for the c_new LN, write h_new/c_new. Total barriers: 3 (was 10).
__device__ __forceinline__ float fast_sigmoid(float x) {
  return __builtin_amdgcn_rcpf(1.0f + __expf(-x));
}
__device__ __forceinline__ float fast_tanh(float x) {
  // 1 - 2/(exp(2x)+1); exp->inf gives 1, exp->0 gives -1 (correct saturation)
  return 1.0f - 2.0f * __builtin_amdgcn_rcpf(__expf(2.0f * x) + 1.0f);
}

__global__ __launch_bounds__(256) void ln_gate_kernel(
    const unsigned short* __restrict__ pih, const unsigned short* __restrict__ phh,
    const float* __restrict__ c, const float* __restrict__ b_ih,
    const float* __restrict__ gamma, const float* __restrict__ beta,
    float* __restrict__ h_out, float* __restrict__ c_out) {
  __shared__ float lds[32];  // [0..15]: stats mu0,rs0,mu1,rs1 per gate; [16..31]: scratch
  const int b = blockIdx.x;
  const int t = threadIdx.x;
  const int wave = t >> 6;   // = gate index in phase A
  const int lane = t & 63;
  const float inv_h = 1.0f / 1024.0f;
  const float eps = 1e-5f;

  // ---- Phase A: per-gate LN stats, wave-local ----
  {
    const size_t rb = (size_t)b * NGATE + wave * HDIM + lane * 16;
    ushort8_t a0 = *(const ushort8_t*)&pih[rb];
    ushort8_t a1 = *(const ushort8_t*)&pih[rb + 8];
    ushort8_t e0 = *(const ushort8_t*)&phh[rb];
    ushort8_t e1 = *(const ushort8_t*)&phh[rb + 8];
    float s0 = 0.f, q0 = 0.f, s1 = 0.f, q1 = 0.f;
#pragma unroll
    for (int r = 0; r < 8; ++r) {
      float va = bf2f(a0[r]), vb = bf2f(a1[r]);
      float ea = bf2f(e0[r]), eb = bf2f(e1[r]);
      s0 += va + vb; q0 += va * va + vb * vb;
      s1 += ea + eb; q1 += ea * ea + eb * eb;
    }
#pragma unroll
    for (int o = 1; o < 64; o <<= 1) {
      s0 += __shfl_xor(s0, o, 64); q0 += __shfl_xor(q0, o, 64);
      s1 += __shfl_xor(s1, o, 64); q1 += __shfl_xor(q1, o, 64);
    }
    if (lane == 0) {
      float mu0 = s0 * inv_h;
      float mu1 = s1 * inv_h;
      lds[wave * 4 + 0] = mu0;
      lds[wave * 4 + 1] = rsqrtf(q0 * inv_h - mu0 * mu0 + eps);
      lds[wave * 4 + 2] = mu1;
      lds[wave * 4 + 3] = rsqrtf(q1 * inv_h - mu1 * mu1 + eps);
    }
  }
  __syncthreads();

  // ---- Phase B: normalize + gate math + c_new LN ----
  const int j = t * 4;
  float gate[4][4];
#pragma unroll
  for (int g = 0; g < 4; ++g) {
    float mu0 = lds[g * 4 + 0], rs0 = lds[g * 4 + 1];
    float mu1 = lds[g * 4 + 2], rs1 = lds[g * 4 + 3];
    ushort4 a4 = *(const ushort4*)&pih[(size_t)b * NGATE + g * HDIM + j];
    ushort4 e4 = *(const ushort4*)&phh[(size_t)b * NGATE + g * HDIM + j];
    float vih[4] = {bf2f(a4.x), bf2f(a4.y), bf2f(a4.z), bf2f(a4.w)};
    float vhh[4] = {bf2f(e4.x), bf2f(e4.y), bf2f(e4.z), bf2f(e4.w)};
    float4 g0 = *(const float4*)&gamma[(2 * g) * HDIM + j];
    float4 b0 = *(const float4*)&beta[(2 * g) * HDIM + j];
    float4 g1 = *(const float4*)&gamma[(2 * g + 1) * HDIM + j];
    float4 b1 = *(const float4*)&beta[(2 * g + 1) * HDIM + j];
    float4 bb = *(const float4*)&b_ih[g * HDIM + j];
    const float* g0p = &g0.x; const float* b0p = &b0.x;
    const float* g1p = &g1.x; const float* b1p = &b1.x;
    const float* bbp = &bb.x;
#pragma unroll
    for (int r = 0; r < 4; ++r) {
      float gih = g0p[r] * ((vih[r] - mu0) * rs0) + b0p[r];
      float ghh = g1p[r] * ((vhh[r] - mu1) * rs1) + b1p[r];
      gate[g][r] = gih + ghh + bbp[r];
    }
  }

  float4 cv4 = *(const float4*)&c[(size_t)b * HDIM + j];
  const float* cvp = &cv4.x;
  float cn[4], ov[4];
  float s2 = 0.f, q2 = 0.f;
#pragma unroll
  for (int r = 0; r < 4; ++r) {
    float iv = fast_sigmoid(gate[0][r]);
    float fv = fast_sigmoid(gate[1][r]);
    float av = fast_tanh(gate[2][r]);
    ov[r] = fast_sigmoid(gate[3][r]);
    float cvn = fv * cvp[r] + iv * av;
    cn[r] = cvn;
    s2 += cvn; q2 += cvn * cvn;
  }
  // block reduction of {s2,q2}
#pragma unroll
  for (int o = 1; o < 64; o <<= 1) {
    s2 += __shfl_xor(s2, o, 64);
    q2 += __shfl_xor(q2, o, 64);
  }
  __syncthreads();  // protect lds reuse (stats already consumed into registers)
  if (lane == 0) { lds[16 + wave * 2] = s2; lds[16 + wave * 2 + 1] = q2; }
  __syncthreads();
  s2 = lds[16] + lds[18] + lds[20] + lds[22];
  q2 = lds[17] + lds[19] + lds[21] + lds[23];
  float mu = s2 * inv_h;
  float rs = rsqrtf(q2 * inv_h - mu * mu + eps);

  float4 g8 = *(const float4*)&gamma[8 * HDIM + j];
  float4 b8 = *(const float4*)&beta[8 * HDIM + j];
  const float* g8p = &g8.x; const float* b8p = &b8.x;
  float4 ho, co;
  float* hop = &ho.x; float* cop = &co.x;
#pragma unroll
  for (int r = 0; r < 4; ++r) {
    float ln = g8p[r] * ((cn[r] - mu) * rs) + b8p[r];
    hop[r] = ov[r] * fast_tanh(ln);
    cop[r] = cn[r];
  }
  *(float4*)&h_out[(size_t)b * HDIM + j] = ho;
  *(float4*)&c_out[(size_t)b * HDIM + j] = co;
}

extern "C" void kernel_launch(void* const* d_in, const int* in_sizes, int n_in,
                              void* d_out, int out_size, void* d_ws, size_t ws_size,
                              hipStream_t stream) {
  const float* x     = (const float*)d_in[0];
  const float* h     = (const float*)d_in[1];
  const float* c     = (const float*)d_in[2];
  const float* w_ih  = (const float*)d_in[3];
  const float* w_hh  = (const float*)d_in[4];
  const float* b_ih  = (const float*)d_in[5];
  const float* gamma = (const float*)d_in[6];
  const float* beta  = (const float*)d_in[7];
  // d_in[8] = time (unused)

  // workspace layout (bytes):
  //   0    xb  bf16 4096x1024 (8MB) | 8M hb | 16M wib | 24M whb
  //   32M  pih bf16 4096x4096 (32MB) | 64M phh (32MB)   total 96 MB
  char* ws = (char*)d_ws;
  unsigned short* xb  = (unsigned short*)(ws);
  unsigned short* hb  = (unsigned short*)(ws + (size_t)8 * 1024 * 1024);
  unsigned short* wib = (unsigned short*)(ws + (size_t)16 * 1024 * 1024);
  unsigned short* whb = (unsigned short*)(ws + (size_t)24 * 1024 * 1024);
  unsigned short* pih = (unsigned short*)(ws + (size_t)32 * 1024 * 1024);
  unsigned short* phh = (unsigned short*)(ws + (size_t)64 * 1024 * 1024);

  dim3 cgrid(4096, 4, 1);  // 4 arrays x 4M elems, 4 elems/thread
  cast_bf16_kernel<<<cgrid, 256, 0, stream>>>(x, h, w_ih, w_hh, xb, hb, wib, whb);

  dim3 ggrid(32, 32, 2);   // 128x128 tiles over 4096x4096; z: 0=ih, 1=hh
  gemm_bt_kernel<<<ggrid, 256, 0, stream>>>(xb, wib, pih, hb, whb, phh);

  float* h_out = (float*)d_out;
  float* c_out = h_out + (size_t)BATCH * HDIM;
  ln_gate_kernel<<<4096, 256, 0, stream>>>(pih, phh, c, b_ih, gamma, beta, h_out, c_out);
}

// Round 4
// 231.771 us; speedup vs baseline: 1.1118x; 1.0722x over previous
//
#include <hip/hip_runtime.h>
#include <hip/hip_bf16.h>
#include <stdint.h>

// Problem: B=4096, I=H=1024. pre_ih = x@w_ih^T, pre_hh = h@w_hh^T (each 4096x4096,
// K=1024), per-gate LN over H, gate math, c_new LN, outputs h_new||c_new (fp32).

#define HDIM 1024
#define BATCH 4096
#define NGATE 4096   /* 4*H */
#define KDIM 1024

typedef __bf16 bf16x8 __attribute__((ext_vector_type(8)));
typedef float f32x4 __attribute__((ext_vector_type(4)));
typedef unsigned short ushort8_t __attribute__((ext_vector_type(8)));

__device__ __forceinline__ unsigned short f2bf(float f) {
  unsigned int u = __builtin_bit_cast(unsigned int, f);
  unsigned int r = (u + 0x7fffu + ((u >> 16) & 1u)) >> 16;
  return (unsigned short)r;
}

__device__ __forceinline__ float bf2f(unsigned short s) {
  unsigned int u = ((unsigned int)s) << 16;
  return __builtin_bit_cast(float, u);
}

__device__ __forceinline__ void gl_lds16(const void* g, void* l) {
  // async global->LDS, 16B per lane; LDS dest = wave-uniform base + lane*16,
  // global addr is per-lane.
  __builtin_amdgcn_global_load_lds(
      (__attribute__((address_space(1))) unsigned int*)g,
      (__attribute__((address_space(3))) unsigned int*)l,
      16, 0, 0);
}

// ---------------- cast fp32 -> bf16 (x, h, w_ih, w_hh) ----------------
__global__ __launch_bounds__(256) void cast_bf16_kernel(
    const float* __restrict__ x, const float* __restrict__ h,
    const float* __restrict__ wi, const float* __restrict__ wh,
    unsigned short* __restrict__ xb, unsigned short* __restrict__ hb,
    unsigned short* __restrict__ wib, unsigned short* __restrict__ whb) {
  const float* src;
  unsigned short* dst;
  switch (blockIdx.y) {
    case 0: src = x;  dst = xb;  break;
    case 1: src = h;  dst = hb;  break;
    case 2: src = wi; dst = wib; break;
    default: src = wh; dst = whb; break;
  }
  size_t i = ((size_t)blockIdx.x * 256 + threadIdx.x) * 4;
  float4 v = *(const float4*)(src + i);
  ushort4 o;
  o.x = f2bf(v.x); o.y = f2bf(v.y); o.z = f2bf(v.z); o.w = f2bf(v.w);
  *(ushort4*)(dst + i) = o;
}

// ---------------- bf16 MFMA GEMM: C[m][n] = sum_k A[m][k]*B[n][k] ----------------
// BM=BN=128, BK=64 (two 16-MFMA k-steps per barrier-pair -> 32 MFMA/barrier,
// halving the vmcnt(0)-before-s_barrier drain fraction vs BK=32).
// LDS rows are 64 elems (128B = 8 granules of 16B). XOR-swizzle: logical
// granule c of row r stored at position c ^ (r&7). Fetch-side (global col
// permutation per lane, since global_load_lds pins LDS dest to lane*16),
// inverted at ds_read: 16-lane read phases hit 8 four-bank groups x 2 lanes
// = conflict-free (m136: 2-way is free).
__global__ __launch_bounds__(256, 4) void gemm_bt_kernel(
    const unsigned short* __restrict__ A0, const unsigned short* __restrict__ B0,
    unsigned short* __restrict__ C0,
    const unsigned short* __restrict__ A1, const unsigned short* __restrict__ B1,
    unsigned short* __restrict__ C1) {
  const unsigned short* A = blockIdx.z ? A1 : A0;
  const unsigned short* B = blockIdx.z ? B1 : B0;
  unsigned short* C = blockIdx.z ? C1 : C0;

  __shared__ alignas(16) unsigned short As[128 * 64];
  __shared__ alignas(16) unsigned short Bs[128 * 64];

  const int tid = threadIdx.x;
  const int wave = tid >> 6;
  const int lane = tid & 63;
  const int bm = blockIdx.x * 128;
  const int bn = blockIdx.y * 128;
  const int wm = (wave >> 1) * 64;
  const int wn = (wave & 1) * 64;

  // staging: each inst covers 8 rows x 128B; lane -> row lane>>3, granule
  // (lane&7)^(lane>>3) (fetch-side swizzle; row&7 == lane>>3 since bases are
  // multiples of 8)
  const int srow = lane >> 3;
  const int scol = (((lane & 7) ^ (lane >> 3)) * 8);

  f32x4 acc[4][4];
#pragma unroll
  for (int i = 0; i < 4; ++i)
#pragma unroll
    for (int j = 0; j < 4; ++j)
#pragma unroll
      for (int r = 0; r < 4; ++r) acc[i][j][r] = 0.0f;

  const int m15 = lane & 15;
  const int quad = lane >> 4;

  for (int k0 = 0; k0 < KDIM; k0 += 64) {
#pragma unroll
    for (int t = 0; t < 4; ++t) {
      int R = wave * 32 + t * 8;  // wave-uniform row base
      gl_lds16(A + (size_t)(bm + R + srow) * KDIM + k0 + scol, &As[R * 64]);
      gl_lds16(B + (size_t)(bn + R + srow) * KDIM + k0 + scol, &Bs[R * 64]);
    }
    __syncthreads();

#pragma unroll
    for (int s = 0; s < 2; ++s) {
      bf16x8 af[4], bfr[4];
#pragma unroll
      for (int i = 0; i < 4; ++i) {
        int row = wm + i * 16 + m15;
        af[i] = *(const bf16x8*)&As[row * 64 + (((4 * s + quad) ^ (m15 & 7)) * 8)];
      }
#pragma unroll
      for (int j = 0; j < 4; ++j) {
        int row = wn + j * 16 + m15;
        bfr[j] = *(const bf16x8*)&Bs[row * 64 + (((4 * s + quad) ^ (m15 & 7)) * 8)];
      }
#pragma unroll
      for (int i = 0; i < 4; ++i)
#pragma unroll
        for (int j = 0; j < 4; ++j)
          acc[i][j] = __builtin_amdgcn_mfma_f32_16x16x32_bf16(af[i], bfr[j], acc[i][j], 0, 0, 0);
    }

    __syncthreads();
  }

  // D layout: row m = (lane>>4)*4 + r, col n = lane&15  [m89/m91 verified]
#pragma unroll
  for (int i = 0; i < 4; ++i)
#pragma unroll
    for (int j = 0; j < 4; ++j)
#pragma unroll
      for (int r = 0; r < 4; ++r) {
        int m = bm + wm + i * 16 + quad * 4 + r;
        int n = bn + wn + j * 16 + m15;
        C[(size_t)m * NGATE + n] = f2bf(acc[i][j][r]);
      }
}

// ---------------- LN + gates + cell update ----------------
// One block per batch row b. Phase A: wave g computes LN stats for gate g
// (ih and hh) via wave-local butterfly reduction (no barriers). Phase B:
// normalize with broadcast stats (re-load is L1/L2-hot), gate math, one block
// reduction for the c_new LN.
__device__ __forceinline__ float fast_sigmoid(float x) {
  return __builtin_amdgcn_rcpf(1.0f + __expf(-x));
}
__device__ __forceinline__ float fast_tanh(float x) {
  // 1 - 2/(exp(2x)+1); exp->inf gives 1, exp->0 gives -1 (correct saturation)
  return 1.0f - 2.0f * __builtin_amdgcn_rcpf(__expf(2.0f * x) + 1.0f);
}

__global__ __launch_bounds__(256) void ln_gate_kernel(
    const unsigned short* __restrict__ pih, const unsigned short* __restrict__ phh,
    const float* __restrict__ c, const float* __restrict__ b_ih,
    const float* __restrict__ gamma, const float* __restrict__ beta,
    float* __restrict__ h_out, float* __restrict__ c_out) {
  __shared__ float lds[32];  // [0..15]: per-gate stats; [16..31]: scratch
  const int b = blockIdx.x;
  const int t = threadIdx.x;
  const int wave = t >> 6;   // = gate index in phase A
  const int lane = t & 63;
  const float inv_h = 1.0f / 1024.0f;
  const float eps = 1e-5f;

  // ---- Phase A: per-gate LN stats, wave-local ----
  {
    const size_t rb = (size_t)b * NGATE + wave * HDIM + lane * 16;
    ushort8_t a0 = *(const ushort8_t*)&pih[rb];
    ushort8_t a1 = *(const ushort8_t*)&pih[rb + 8];
    ushort8_t e0 = *(const ushort8_t*)&phh[rb];
    ushort8_t e1 = *(const ushort8_t*)&phh[rb + 8];
    float s0 = 0.f, q0 = 0.f, s1 = 0.f, q1 = 0.f;
#pragma unroll
    for (int r = 0; r < 8; ++r) {
      float va = bf2f(a0[r]), vb = bf2f(a1[r]);
      float ea = bf2f(e0[r]), eb = bf2f(e1[r]);
      s0 += va + vb; q0 += va * va + vb * vb;
      s1 += ea + eb; q1 += ea * ea + eb * eb;
    }
#pragma unroll
    for (int o = 1; o < 64; o <<= 1) {
      s0 += __shfl_xor(s0, o, 64); q0 += __shfl_xor(q0, o, 64);
      s1 += __shfl_xor(s1, o, 64); q1 += __shfl_xor(q1, o, 64);
    }
    if (lane == 0) {
      float mu0 = s0 * inv_h;
      float mu1 = s1 * inv_h;
      lds[wave * 4 + 0] = mu0;
      lds[wave * 4 + 1] = rsqrtf(q0 * inv_h - mu0 * mu0 + eps);
      lds[wave * 4 + 2] = mu1;
      lds[wave * 4 + 3] = rsqrtf(q1 * inv_h - mu1 * mu1 + eps);
    }
  }
  __syncthreads();

  // ---- Phase B: normalize + gate math + c_new LN ----
  const int j = t * 4;
  float gate[4][4];
#pragma unroll
  for (int g = 0; g < 4; ++g) {
    float mu0 = lds[g * 4 + 0], rs0 = lds[g * 4 + 1];
    float mu1 = lds[g * 4 + 2], rs1 = lds[g * 4 + 3];
    ushort4 a4 = *(const ushort4*)&pih[(size_t)b * NGATE + g * HDIM + j];
    ushort4 e4 = *(const ushort4*)&phh[(size_t)b * NGATE + g * HDIM + j];
    float vih[4] = {bf2f(a4.x), bf2f(a4.y), bf2f(a4.z), bf2f(a4.w)};
    float vhh[4] = {bf2f(e4.x), bf2f(e4.y), bf2f(e4.z), bf2f(e4.w)};
    float4 g0 = *(const float4*)&gamma[(2 * g) * HDIM + j];
    float4 b0 = *(const float4*)&beta[(2 * g) * HDIM + j];
    float4 g1 = *(const float4*)&gamma[(2 * g + 1) * HDIM + j];
    float4 b1 = *(const float4*)&beta[(2 * g + 1) * HDIM + j];
    float4 bb = *(const float4*)&b_ih[g * HDIM + j];
    const float* g0p = &g0.x; const float* b0p = &b0.x;
    const float* g1p = &g1.x; const float* b1p = &b1.x;
    const float* bbp = &bb.x;
#pragma unroll
    for (int r = 0; r < 4; ++r) {
      float gih = g0p[r] * ((vih[r] - mu0) * rs0) + b0p[r];
      float ghh = g1p[r] * ((vhh[r] - mu1) * rs1) + b1p[r];
      gate[g][r] = gih + ghh + bbp[r];
    }
  }

  float4 cv4 = *(const float4*)&c[(size_t)b * HDIM + j];
  const float* cvp = &cv4.x;
  float cn[4], ov[4];
  float s2 = 0.f, q2 = 0.f;
#pragma unroll
  for (int r = 0; r < 4; ++r) {
    float iv = fast_sigmoid(gate[0][r]);
    float fv = fast_sigmoid(gate[1][r]);
    float av = fast_tanh(gate[2][r]);
    ov[r] = fast_sigmoid(gate[3][r]);
    float cvn = fv * cvp[r] + iv * av;
    cn[r] = cvn;
    s2 += cvn; q2 += cvn * cvn;
  }
#pragma unroll
  for (int o = 1; o < 64; o <<= 1) {
    s2 += __shfl_xor(s2, o, 64);
    q2 += __shfl_xor(q2, o, 64);
  }
  __syncthreads();  // stats already consumed into registers
  if (lane == 0) { lds[16 + wave * 2] = s2; lds[16 + wave * 2 + 1] = q2; }
  __syncthreads();
  s2 = lds[16] + lds[18] + lds[20] + lds[22];
  q2 = lds[17] + lds[19] + lds[21] + lds[23];
  float mu = s2 * inv_h;
  float rs = rsqrtf(q2 * inv_h - mu * mu + eps);

  float4 g8 = *(const float4*)&gamma[8 * HDIM + j];
  float4 b8 = *(const float4*)&beta[8 * HDIM + j];
  const float* g8p = &g8.x; const float* b8p = &b8.x;
  float4 ho, co;
  float* hop = &ho.x; float* cop = &co.x;
#pragma unroll
  for (int r = 0; r < 4; ++r) {
    float ln = g8p[r] * ((cn[r] - mu) * rs) + b8p[r];
    hop[r] = ov[r] * fast_tanh(ln);
    cop[r] = cn[r];
  }
  *(float4*)&h_out[(size_t)b * HDIM + j] = ho;
  *(float4*)&c_out[(size_t)b * HDIM + j] = co;
}

extern "C" void kernel_launch(void* const* d_in, const int* in_sizes, int n_in,
                              void* d_out, int out_size, void* d_ws, size_t ws_size,
                              hipStream_t stream) {
  const float* x     = (const float*)d_in[0];
  const float* h     = (const float*)d_in[1];
  const float* c     = (const float*)d_in[2];
  const float* w_ih  = (const float*)d_in[3];
  const float* w_hh  = (const float*)d_in[4];
  const float* b_ih  = (const float*)d_in[5];
  const float* gamma = (const float*)d_in[6];
  const float* beta  = (const float*)d_in[7];
  // d_in[8] = time (unused)

  // workspace layout (bytes):
  //   0    xb  bf16 4096x1024 (8MB) | 8M hb | 16M wib | 24M whb
  //   32M  pih bf16 4096x4096 (32MB) | 64M phh (32MB)   total 96 MB
  char* ws = (char*)d_ws;
  unsigned short* xb  = (unsigned short*)(ws);
  unsigned short* hb  = (unsigned short*)(ws + (size_t)8 * 1024 * 1024);
  unsigned short* wib = (unsigned short*)(ws + (size_t)16 * 1024 * 1024);
  unsigned short* whb = (unsigned short*)(ws + (size_t)24 * 1024 * 1024);
  unsigned short* pih = (unsigned short*)(ws + (size_t)32 * 1024 * 1024);
  unsigned short* phh = (unsigned short*)(ws + (size_t)64 * 1024 * 1024);

  dim3 cgrid(4096, 4, 1);  // 4 arrays x 4M elems, 4 elems/thread
  cast_bf16_kernel<<<cgrid, 256, 0, stream>>>(x, h, w_ih, w_hh, xb, hb, wib, whb);

  dim3 ggrid(32, 32, 2);   // 128x128 tiles over 4096x4096; z: 0=ih, 1=hh
  gemm_bt_kernel<<<ggrid, 256, 0, stream>>>(xb, wib, pih, hb, whb, phh);

  float* h_out = (float*)d_out;
  float* c_out = h_out + (size_t)BATCH * HDIM;
  ln_gate_kernel<<<4096, 256, 0, stream>>>(pih, phh, c, b_ih, gamma, beta, h_out, c_out);
}